// Round 1
// baseline (655.800 us; speedup 1.0000x reference)
//
#include <hip/hip_runtime.h>
#include <math.h>

#define N_NODES 650
#define DIM     512
#define E_RAW   150000
#define E_TOT   150650

// ---------- ordered-float tricks for atomicMax over signed floats ----------
__device__ __forceinline__ unsigned f2ord(float f) {
    unsigned u = __float_as_uint(f);
    return (u & 0x80000000u) ? ~u : (u | 0x80000000u);
}
__device__ __forceinline__ float ord2f(unsigned k) {
    return (k & 0x80000000u) ? __uint_as_float(k ^ 0x80000000u)
                             : __uint_as_float(~k);
}

// ---------- concat x_s [400,512] + x_t [250,512] -> xin [650,512] ----------
__global__ void concat_kernel(const float* __restrict__ xs,
                              const float* __restrict__ xt,
                              float* __restrict__ xin) {
    int i = blockIdx.x * blockDim.x + threadIdx.x;
    if (i >= N_NODES * DIM) return;
    int row = i / DIM;
    xin[i] = (row < 400) ? xs[i] : xt[i - 400 * DIM];
}

// ---------- tiled fp32 GEMM: C[M,N] = A[M,K] @ B[K,N] (+bias, act) ----------
// act: 0 = none, 1 = relu, 2 = leaky_relu(0.01)
#define BM 64
#define BN 64
#define BK 16
__global__ __launch_bounds__(256)
void gemm_kernel(const float* __restrict__ A, const float* __restrict__ B,
                 const float* __restrict__ bias, float* __restrict__ C,
                 int M, int N, int K, int act) {
    __shared__ float As[BM][BK + 1];
    __shared__ float Bs[BK][BN];
    int tx = threadIdx.x % 16;       // column group
    int ty = threadIdx.x / 16;       // row group
    int row0 = blockIdx.y * BM, col0 = blockIdx.x * BN;
    float acc[4][4] = {};
    for (int k0 = 0; k0 < K; k0 += BK) {
        for (int l = threadIdx.x; l < BM * BK; l += 256) {
            int r = l / BK, c = l % BK;
            int gr = row0 + r, gc = k0 + c;
            As[r][c] = (gr < M && gc < K) ? A[gr * K + gc] : 0.f;
        }
        for (int l = threadIdx.x; l < BK * BN; l += 256) {
            int r = l / BN, c = l % BN;
            int gr = k0 + r, gc = col0 + c;
            Bs[r][c] = (gr < K && gc < N) ? B[gr * N + gc] : 0.f;
        }
        __syncthreads();
        #pragma unroll
        for (int kk = 0; kk < BK; kk++) {
            float a[4], b[4];
            #pragma unroll
            for (int i = 0; i < 4; i++) a[i] = As[ty * 4 + i][kk];
            #pragma unroll
            for (int j = 0; j < 4; j++) b[j] = Bs[kk][tx * 4 + j];
            #pragma unroll
            for (int i = 0; i < 4; i++)
                #pragma unroll
                for (int j = 0; j < 4; j++)
                    acc[i][j] += a[i] * b[j];
        }
        __syncthreads();
    }
    #pragma unroll
    for (int i = 0; i < 4; i++) {
        int gr = row0 + ty * 4 + i;
        if (gr >= M) continue;
        #pragma unroll
        for (int j = 0; j < 4; j++) {
            int gc = col0 + tx * 4 + j;
            if (gc >= N) continue;
            float v = acc[i][j];
            if (bias) v += bias[gc];
            if (act == 1) v = v > 0.f ? v : 0.f;
            else if (act == 2) v = v > 0.f ? v : 0.01f * v;
            C[gr * N + gc] = v;
        }
    }
}

// ---------- per-node attention logits: als[n]=h[n].a_src, ald[n]=h[n].a_dst ----------
__global__ void logits_kernel(const float* __restrict__ h,
                              const float* __restrict__ asrc,
                              const float* __restrict__ adst,
                              float* __restrict__ als, float* __restrict__ ald) {
    int n = blockIdx.x;
    int lane = threadIdx.x;   // 64 threads = 1 wave
    float ss = 0.f, sd = 0.f;
    for (int d = lane; d < DIM; d += 64) {
        float v = h[n * DIM + d];
        ss += v * asrc[d];
        sd += v * adst[d];
    }
    for (int o = 32; o > 0; o >>= 1) {
        ss += __shfl_down(ss, o);
        sd += __shfl_down(sd, o);
    }
    if (lane == 0) { als[n] = ss; ald[n] = sd; }
}

__device__ __forceinline__ void edge_sd(const int* __restrict__ ei, int i, int& s, int& d) {
    if (i < E_RAW) { s = ei[i]; d = ei[E_RAW + i]; }
    else           { s = d = i - E_RAW; }
}

// ---------- edge pass 1: e = leaky_relu(als[src]+ald[dst],0.2); segment max ----------
__global__ void edge_logit_max(const int* __restrict__ ei,
                               const float* __restrict__ als,
                               const float* __restrict__ ald,
                               float* __restrict__ e, unsigned* __restrict__ mkey) {
    int i = blockIdx.x * blockDim.x + threadIdx.x;
    if (i >= E_TOT) return;
    int s, d; edge_sd(ei, i, s, d);
    float v = als[s] + ald[d];
    v = v > 0.f ? v : 0.2f * v;
    e[i] = v;
    atomicMax(mkey + d, f2ord(v));
}

// ---------- edge pass 2: ex = exp(e - m[dst]); segment sum ----------
__global__ void edge_exp_sum(const int* __restrict__ ei,
                             const unsigned* __restrict__ mkey,
                             float* __restrict__ e, float* __restrict__ ssum) {
    int i = blockIdx.x * blockDim.x + threadIdx.x;
    if (i >= E_TOT) return;
    int s, d; edge_sd(ei, i, s, d);
    float ex = expf(e[i] - ord2f(mkey[d]));
    e[i] = ex;
    atomicAdd(ssum + d, ex);
}

// ---------- edge pass 3: alpha scatter into dense A[dst][src] ----------
__global__ void edge_alpha_scatter(const int* __restrict__ ei,
                                   const float* __restrict__ e,
                                   const float* __restrict__ ssum,
                                   float* __restrict__ Amat) {
    int i = blockIdx.x * blockDim.x + threadIdx.x;
    if (i >= E_TOT) return;
    int s, d; edge_sd(ei, i, s, d);
    float alpha = e[i] / (ssum[d] + 1e-16f);
    atomicAdd(Amat + d * N_NODES + s, alpha);
}

// ---------- final: out[b] = sigmoid( dot(flat[b*650: b*650+650], fc_w) + fc_b ) ----------
__global__ void final_kernel(const float* __restrict__ o2,
                             const float* __restrict__ fcw,
                             const float* __restrict__ fcb,
                             float* __restrict__ out) {
    int b = blockIdx.x;
    int lane = threadIdx.x;   // 64 threads
    float s = 0.f;
    for (int i = lane; i < N_NODES; i += 64)
        s += o2[b * N_NODES + i] * fcw[i];
    for (int o = 32; o > 0; o >>= 1) s += __shfl_down(s, o);
    if (lane == 0) out[b] = 1.f / (1.f + expf(-(s + fcb[0])));
}

extern "C" void kernel_launch(void* const* d_in, const int* in_sizes, int n_in,
                              void* d_out, int out_size, void* d_ws, size_t ws_size,
                              hipStream_t stream) {
    const float* x_s   = (const float*)d_in[0];
    const float* x_t   = (const float*)d_in[1];
    const int*   ei    = (const int*)d_in[2];
    // d_in[3] distances, d_in[4] batch: unused
    const float* W1    = (const float*)d_in[5];
    const float* asrc1 = (const float*)d_in[6];
    const float* adst1 = (const float*)d_in[7];
    const float* b1    = (const float*)d_in[8];
    const float* W4    = (const float*)d_in[9];
    const float* asrc4 = (const float*)d_in[10];
    const float* adst4 = (const float*)d_in[11];
    const float* b4    = (const float*)d_in[12];
    const float* fcw   = (const float*)d_in[13];
    const float* fcb   = (const float*)d_in[14];
    float* out = (float*)d_out;

    float* ws = (float*)d_ws;
    // workspace layout (4-byte units)
    const size_t A_ELEMS = (size_t)N_NODES * N_NODES;   // 422500
    float*    A1   = ws;                                //  zeroed
    float*    A2   = A1 + A_ELEMS;                      //  zeroed
    unsigned* m1   = (unsigned*)(A2 + A_ELEMS);         //  zeroed (ordered-min)
    float*    s1   = (float*)(m1 + N_NODES);            //  zeroed
    unsigned* m2   = (unsigned*)(s1 + N_NODES);         //  zeroed
    float*    s2   = (float*)(m2 + N_NODES);            //  zeroed
    float*    xin  = s2 + N_NODES;
    float*    h1   = xin + (size_t)N_NODES * DIM;
    float*    o1   = h1 + (size_t)N_NODES * DIM;
    float*    h2   = o1 + (size_t)N_NODES * DIM;
    float*    o2   = h2 + (size_t)N_NODES * DIM;
    float*    als1 = o2 + (size_t)N_NODES * DIM;
    float*    ald1 = als1 + N_NODES;
    float*    als2 = ald1 + N_NODES;
    float*    ald2 = als2 + N_NODES;
    float*    ebuf = ald2 + N_NODES;

    // zero A1,A2,m1,s1,m2,s2 in one shot (contiguous)
    size_t zero_bytes = (2 * A_ELEMS + 4 * N_NODES) * sizeof(float);
    hipMemsetAsync(d_ws, 0, zero_bytes, stream);

    dim3 gGemm((DIM + BN - 1) / BN, (N_NODES + BM - 1) / BM);
    int eBlocks = (E_TOT + 255) / 256;

    // concat
    concat_kernel<<<(N_NODES * DIM + 255) / 256, 256, 0, stream>>>(x_s, x_t, xin);

    // ---- layer 1 ----
    gemm_kernel<<<gGemm, 256, 0, stream>>>(xin, W1, nullptr, h1, N_NODES, DIM, DIM, 0);
    logits_kernel<<<N_NODES, 64, 0, stream>>>(h1, asrc1, adst1, als1, ald1);
    edge_logit_max<<<eBlocks, 256, 0, stream>>>(ei, als1, ald1, ebuf, m1);
    edge_exp_sum<<<eBlocks, 256, 0, stream>>>(ei, m1, ebuf, s1);
    edge_alpha_scatter<<<eBlocks, 256, 0, stream>>>(ei, ebuf, s1, A1);
    gemm_kernel<<<gGemm, 256, 0, stream>>>(A1, h1, b1, o1, N_NODES, DIM, N_NODES, 1);

    // ---- layer 2 ----
    gemm_kernel<<<gGemm, 256, 0, stream>>>(o1, W4, nullptr, h2, N_NODES, DIM, DIM, 0);
    logits_kernel<<<N_NODES, 64, 0, stream>>>(h2, asrc4, adst4, als2, ald2);
    edge_logit_max<<<eBlocks, 256, 0, stream>>>(ei, als2, ald2, ebuf, m2);
    edge_exp_sum<<<eBlocks, 256, 0, stream>>>(ei, m2, ebuf, s2);
    edge_alpha_scatter<<<eBlocks, 256, 0, stream>>>(ei, ebuf, s2, A2);
    gemm_kernel<<<gGemm, 256, 0, stream>>>(A2, h2, b4, o2, N_NODES, DIM, N_NODES, 2);

    // ---- final linear + sigmoid ----
    final_kernel<<<512, 64, 0, stream>>>(o2, fcw, fcb, out);
}

// Round 2
// 439.652 us; speedup vs baseline: 1.4916x; 1.4916x over previous
//
#include <hip/hip_runtime.h>
#include <math.h>

#define N_NODES 650
#define DIM     512
#define E_RAW   150000
#define E_TOT   150650

#define BM 64
#define BN 64
#define BK 32

// ---------------- split-K GEMM, atomic fp32 accumulation ----------------
// C[M,N] += A_chunk @ B_chunk  (C must be pre-zeroed)
// a_mode: 0 = plain A
//         1 = A is concat(xs=A, xt=Axt) along rows (row<400 -> A, else Axt)
//         2 = A element gets epilogue of previous layer:
//             v = relu( A[r,c] / (srow[r]+1e-16) + abias[c] )
__global__ __launch_bounds__(256)
void gemm_sk(const float* __restrict__ A, const float* __restrict__ Axt,
             const float* __restrict__ srow, const float* __restrict__ abias,
             const float* __restrict__ B, float* __restrict__ C,
             int M, int N, int K, int a_mode, int chunk) {
    __shared__ float As[BM][BK + 1];
    __shared__ float Bs[BK][BN];
    int t = threadIdx.x;
    int tx = t & 15, ty = t >> 4;
    int row0 = blockIdx.y * BM, col0 = blockIdx.x * BN;
    int k0 = blockIdx.z * chunk;
    int k1 = min(k0 + chunk, K);
    float acc[4][4] = {};

    for (int kb = k0; kb < k1; kb += BK) {
        // stage A: As[m][kk] = Aelem(row0+m, kb+kk)
        for (int l = t; l < BM * BK; l += 256) {
            int m = l >> 5, kk = l & 31;
            int gr = row0 + m, gk = kb + kk;
            float v = 0.f;
            if (gr < M && gk < k1) {
                if (a_mode == 0) {
                    v = A[gr * K + gk];
                } else if (a_mode == 1) {
                    v = (gr < 400) ? A[gr * DIM + gk] : Axt[(gr - 400) * DIM + gk];
                } else {
                    v = A[gr * K + gk] / (srow[gr] + 1e-16f) + abias[gk];
                    v = v > 0.f ? v : 0.f;
                }
            }
            As[m][kk] = v;
        }
        // stage B: Bs[kk][n] = B[kb+kk][col0+n]
        for (int l = t; l < BK * BN; l += 256) {
            int kk = l >> 6, n = l & 63;
            int gk = kb + kk, gn = col0 + n;
            Bs[kk][n] = (gk < k1 && gn < N) ? B[gk * N + gn] : 0.f;
        }
        __syncthreads();
        #pragma unroll
        for (int kk = 0; kk < BK; kk++) {
            float a0 = As[ty * 4 + 0][kk];
            float a1 = As[ty * 4 + 1][kk];
            float a2 = As[ty * 4 + 2][kk];
            float a3 = As[ty * 4 + 3][kk];
            float4 b = *(const float4*)&Bs[kk][tx * 4];
            acc[0][0] += a0 * b.x; acc[0][1] += a0 * b.y; acc[0][2] += a0 * b.z; acc[0][3] += a0 * b.w;
            acc[1][0] += a1 * b.x; acc[1][1] += a1 * b.y; acc[1][2] += a1 * b.z; acc[1][3] += a1 * b.w;
            acc[2][0] += a2 * b.x; acc[2][1] += a2 * b.y; acc[2][2] += a2 * b.z; acc[2][3] += a2 * b.w;
            acc[3][0] += a3 * b.x; acc[3][1] += a3 * b.y; acc[3][2] += a3 * b.z; acc[3][3] += a3 * b.w;
        }
        __syncthreads();
    }
    #pragma unroll
    for (int i = 0; i < 4; i++) {
        int gr = row0 + ty * 4 + i;
        if (gr >= M) continue;
        #pragma unroll
        for (int j = 0; j < 4; j++) {
            int gc = col0 + tx * 4 + j;
            if (gc < N) atomicAdd(&C[gr * N + gc], acc[i][j]);
        }
    }
}

// -------- per-node logits: als[n]=h[n].asrc, ald[n]=h[n].adst (4 nodes/block) --------
__global__ void logits_kernel(const float* __restrict__ h,
                              const float* __restrict__ asrc,
                              const float* __restrict__ adst,
                              float* __restrict__ als, float* __restrict__ ald) {
    int n = blockIdx.x * 4 + (threadIdx.x >> 6);
    int lane = threadIdx.x & 63;
    if (n >= N_NODES) return;
    float ss = 0.f, sd = 0.f;
    for (int d = lane; d < DIM; d += 64) {
        float v = h[n * DIM + d];
        ss += v * asrc[d];
        sd += v * adst[d];
    }
    #pragma unroll
    for (int o = 32; o > 0; o >>= 1) {
        ss += __shfl_down(ss, o);
        sd += __shfl_down(sd, o);
    }
    if (lane == 0) { als[n] = ss; ald[n] = sd; }
}

// -------- fused edge pass: ex = exp(leaky(als[s]+ald[d],0.2));
//          ssum[d] += ex;  Amat[d][s] += ex  (normalization deferred) --------
__global__ void edge_fused(const int* __restrict__ ei,
                           const float* __restrict__ als,
                           const float* __restrict__ ald,
                           float* __restrict__ ssum, float* __restrict__ Amat) {
    int i = blockIdx.x * blockDim.x + threadIdx.x;
    if (i >= E_TOT) return;
    int s, d;
    if (i < E_RAW) { s = ei[i]; d = ei[E_RAW + i]; }
    else           { s = d = i - E_RAW; }
    float v = als[s] + ald[d];
    v = v > 0.f ? v : 0.2f * v;
    float ex = expf(v);
    atomicAdd(ssum + d, ex);
    atomicAdd(Amat + d * N_NODES + s, ex);
}

// -------- final: epilogue(o2raw) -> reshape(512,650) -> @fc_w + fc_b -> sigmoid ----
// o2[r][c] = leaky( o2raw[r][c]/(s2[r]+1e-16) + b4[c], 0.01 ); flat idx f=b*650+i
__global__ void final_kernel(const float* __restrict__ o2raw,
                             const float* __restrict__ s2,
                             const float* __restrict__ b4,
                             const float* __restrict__ fcw,
                             const float* __restrict__ fcb,
                             float* __restrict__ out) {
    int b = blockIdx.x * 4 + (threadIdx.x >> 6);
    int lane = threadIdx.x & 63;
    if (b >= 512) return;
    float s = 0.f;
    for (int i = lane; i < N_NODES; i += 64) {
        int f = b * N_NODES + i;
        int r = f >> 9, c = f & 511;
        float v = o2raw[f] / (s2[r] + 1e-16f) + b4[c];
        v = v > 0.f ? v : 0.01f * v;
        s += v * fcw[i];
    }
    #pragma unroll
    for (int o = 32; o > 0; o >>= 1) s += __shfl_down(s, o);
    if (lane == 0) out[b] = 1.f / (1.f + expf(-(s + fcb[0])));
}

extern "C" void kernel_launch(void* const* d_in, const int* in_sizes, int n_in,
                              void* d_out, int out_size, void* d_ws, size_t ws_size,
                              hipStream_t stream) {
    const float* x_s   = (const float*)d_in[0];
    const float* x_t   = (const float*)d_in[1];
    const int*   ei    = (const int*)d_in[2];
    const float* W1    = (const float*)d_in[5];
    const float* asrc1 = (const float*)d_in[6];
    const float* adst1 = (const float*)d_in[7];
    const float* b1    = (const float*)d_in[8];
    const float* W4    = (const float*)d_in[9];
    const float* asrc4 = (const float*)d_in[10];
    const float* adst4 = (const float*)d_in[11];
    const float* b4    = (const float*)d_in[12];
    const float* fcw   = (const float*)d_in[13];
    const float* fcb   = (const float*)d_in[14];
    float* out = (float*)d_out;

    float* ws = (float*)d_ws;
    const size_t A_ELEMS = (size_t)N_NODES * N_NODES;   // 422500
    const size_t H_ELEMS = (size_t)N_NODES * DIM;       // 332800
    // zeroed region (atomic targets), contiguous:
    float* A1 = ws;
    float* A2 = A1 + A_ELEMS;
    float* h1 = A2 + A_ELEMS;
    float* h2 = h1 + H_ELEMS;
    float* o1 = h2 + H_ELEMS;
    float* o2 = o1 + H_ELEMS;
    float* s1 = o2 + H_ELEMS;
    float* s2 = s1 + N_NODES;
    size_t zero_elems = 2 * A_ELEMS + 4 * H_ELEMS + 2 * N_NODES;
    // non-zeroed scratch:
    float* als1 = s2 + N_NODES;
    float* ald1 = als1 + N_NODES;
    float* als2 = ald1 + N_NODES;
    float* ald2 = als2 + N_NODES;

    hipMemsetAsync(d_ws, 0, zero_elems * sizeof(float), stream);

    dim3 g512(DIM / BN, (N_NODES + BM - 1) / BM, 8);   // K=512, chunk 64
    dim3 g650(DIM / BN, (N_NODES + BM - 1) / BM, 7);   // K=650, chunk 96
    int eBlocks = (E_TOT + 255) / 256;
    int nBlocks = (N_NODES + 3) / 4;

    // ---- layer 1 ----
    gemm_sk<<<g512, 256, 0, stream>>>(x_s, x_t, nullptr, nullptr, W1, h1,
                                      N_NODES, DIM, DIM, 1, 64);
    logits_kernel<<<nBlocks, 256, 0, stream>>>(h1, asrc1, adst1, als1, ald1);
    edge_fused<<<eBlocks, 256, 0, stream>>>(ei, als1, ald1, s1, A1);
    gemm_sk<<<g650, 256, 0, stream>>>(A1, nullptr, nullptr, nullptr, h1, o1,
                                      N_NODES, DIM, N_NODES, 0, 96);

    // ---- layer 2 (o1 epilogue fused into A-load: /s1 + b1, relu) ----
    gemm_sk<<<g512, 256, 0, stream>>>(o1, nullptr, s1, b1, W4, h2,
                                      N_NODES, DIM, DIM, 2, 64);
    logits_kernel<<<nBlocks, 256, 0, stream>>>(h2, asrc4, adst4, als2, ald2);
    edge_fused<<<eBlocks, 256, 0, stream>>>(ei, als2, ald2, s2, A2);
    gemm_sk<<<g650, 256, 0, stream>>>(A2, nullptr, nullptr, nullptr, h2, o2,
                                      N_NODES, DIM, N_NODES, 0, 96);

    // ---- final (o2 epilogue fused: /s2 + b4, leaky 0.01) ----
    final_kernel<<<128, 256, 0, stream>>>(o2, s2, b4, fcw, fcb, out);
}